// Round 10
// baseline (198.684 us; speedup 1.0000x reference)
//
#include <hip/hip_runtime.h>
#include <math.h>

#define HH 256
#define NN 64
#define LL 4096
#define BB 8
#define TK 32            // tokens per gconv block
#define NCH (LL / TK)    // 128 chunks per batch

// ws layout (floats):
//   Ktrev (float [L][H])   @ 0        (1048576)   Ktrev[i][h] = K[h][L-1-i]
//   y     (float [B][H])   @ 1048576  (2048)      atomic-accumulated conv
//   ticket(int  [B])       @ 1050624  (8)

// k1: K-materialization, one block per h (proven spill-free scheme):
//   K[h,l] = Re( sum_n w[h,n] * dA[h,n]^l ),  w = 2*C0*dB
//   wave w owns l-range [512w,512w+512), lane owns l%64, n serial; pow
//   table dA_n^lane in padded LDS; store TRANSPOSED+reversed. Block 0 also
//   zero-inits y and the per-batch tickets (stream order: before gconv).
__global__ __launch_bounds__(512) void kmat_kernel(
    const float* __restrict__ log_dt, const float* __restrict__ A_log_re,
    const float* __restrict__ A_im, const float* __restrict__ B_re,
    const float* __restrict__ B_im, const float* __restrict__ C_re,
    const float* __restrict__ C_im, float* __restrict__ Ktrev,
    float* __restrict__ y, int* __restrict__ ticket) {
    __shared__ struct {
        float powR[64][65]; float powI[64][65];
        float2 dAt[64]; float2 e64t[64]; float2 W2[8][64];
    } sk;
    int t = threadIdx.x;
    int h = blockIdx.x;
    int w = __builtin_amdgcn_readfirstlane(t >> 6);   // wave id 0..7
    int lane = t & 63;
    if (h == 0) {   // per-iteration init (ws is re-poisoned each iter)
        #pragma unroll
        for (int i = 0; i < BB * HH / 512; ++i) y[i * 512 + t] = 0.0f;
        if (t < BB) ticket[t] = 0;
    }
    // -- stage 1 (wave 0): per-n constants --
    if (t < NN) {
        int n = t;
        int idx = h * NN + n;
        float dt = expf(log_dt[h]);
        float Are = -expf(A_log_re[idx]);
        float Aim = A_im[idx];
        float ea = expf(dt * Are);
        float sn, cs;
        sincosf(dt * Aim, &sn, &cs);
        float dAre = ea * cs, dAim = ea * sn;
        float numre = dAre - 1.0f, numim = dAim;
        float den = Are * Are + Aim * Aim;
        float qre = (numre * Are + numim * Aim) / den;
        float qim = (numim * Are - numre * Aim) / den;
        float bre = B_re[idx], bim = B_im[idx];
        float dBre = bre * qre - bim * qim;
        float dBim = bre * qim + bim * qre;
        float cre = C_re[idx], cim = C_im[idx];
        float wre = 2.0f * (cre * dBre - cim * dBim);
        float wim = 2.0f * (cre * dBim + cim * dBre);
        sk.dAt[n] = make_float2(dAre, dAim);
        // e64 = dA^64 (6 squarings)
        float pr = dAre, pi = dAim;
        #pragma unroll
        for (int kq = 0; kq < 6; ++kq) {
            float nr = pr * pr - pi * pi;
            pi = 2.0f * pr * pi; pr = nr;
        }
        sk.e64t[n] = make_float2(pr, pi);
        // dA^512 = 3 more squarings
        #pragma unroll
        for (int kq = 0; kq < 3; ++kq) {
            float nr = pr * pr - pi * pi;
            pi = 2.0f * pr * pi; pr = nr;
        }
        // W2[k][n] = w_n * dA^(512k)
        float qr2 = wre, qi2 = wim;
        #pragma unroll
        for (int kk = 0; kk < 8; ++kk) {
            sk.W2[kk][n] = make_float2(qr2, qi2);
            float nr = qr2 * pr - qi2 * pi, ni = qr2 * pi + qi2 * pr;
            qr2 = nr; qi2 = ni;
        }
    }
    __syncthreads();
    // -- stage 2 (all waves): pow table, wave w fills rows 8w..8w+7 --
    {
        float2 a = sk.dAt[lane];             // dA_n, n = lane
        float br = a.x, bi = a.y;            // -> dA^8
        #pragma unroll
        for (int kq = 0; kq < 3; ++kq) {
            float nr = br * br - bi * bi;
            bi = 2.0f * br * bi; br = nr;
        }
        float pr = 1.0f, pi = 0.0f;          // d8^w (w uniform)
        #pragma unroll
        for (int bit = 0; bit < 3; ++bit) {
            if ((w >> bit) & 1) {
                float tr = pr * br - pi * bi;
                pi = pr * bi + pi * br; pr = tr;
            }
            float t2 = br * br - bi * bi;
            bi = 2.0f * br * bi; br = t2;
        }
        #pragma unroll
        for (int i = 0; i < 8; ++i) {        // pow[8w+i][n] = dA_n^(8w+i)
            sk.powR[8 * w + i][lane] = pr;
            sk.powI[8 * w + i][lane] = pi;
            float tr = pr * a.x - pi * a.y;
            pi = pr * a.y + pi * a.x; pr = tr;
        }
    }
    __syncthreads();
    // -- stage 3: thread owns l = 512w + 64j + lane, n serial --
    float kacc[8];
    #pragma unroll
    for (int j = 0; j < 8; ++j) kacc[j] = 0.0f;
    #pragma unroll 2
    for (int n = 0; n < NN; ++n) {
        float Pr = sk.powR[lane][n];         // conflict-free (pad 65)
        float Pi = sk.powI[lane][n];
        float2 E = sk.e64t[n];               // uniform broadcast
        float2 Wn = sk.W2[w][n];             // uniform broadcast
        float vr = Wn.x * Pr - Wn.y * Pi;
        float vi = Wn.x * Pi + Wn.y * Pr;
        #pragma unroll
        for (int j = 0; j < 8; ++j) {
            kacc[j] += vr;
            float tr = vr * E.x - vi * E.y;
            vi = vr * E.y + vi * E.x; vr = tr;
        }
    }
    // -- store transposed + reversed --
    #pragma unroll
    for (int j = 0; j < 8; ++j) {
        int l = w * 512 + j * 64 + lane;
        Ktrev[(long)(LL - 1 - l) * HH + h] = kacc[j];
    }
}

// k2: fused gather-conv + last-block output finisher. Block = (b, 32-token
// chunk). Stage Ktrev slice [32][256] via global_load_lds; stream emb rows
// coalesced; 32 FMA/thread; one atomicAdd per thread into y[b][h]. Then:
// each wave drains vmcnt (compiler emits vmcnt(0) before s_barrier), t0
// takes a relaxed returning ticket; the block drawing old==NCH-1 knows all
// y-adds for its batch reached the coherence point -> runs GELU + 512-row
// GEMV + GLU with all 4 waves. No fences, no spin, no residency assumption.
__global__ __launch_bounds__(256) void gconv_kernel(
    const int* __restrict__ ids, const float* __restrict__ emb,
    const float* __restrict__ Ktrev, float* __restrict__ y,
    int* __restrict__ ticket, const float* __restrict__ Dv,
    const float* __restrict__ W, const float* __restrict__ bvec,
    float* __restrict__ out) {
    __shared__ float Kls[TK * HH];   // 32 KB
    __shared__ int idsl[TK];
    __shared__ float gs[HH];         // finisher: gelu row (1 KB)
    __shared__ float zbuf[2 * HH];   // finisher: z (2 KB)
    __shared__ int role;
    int t = threadIdx.x;
    int b = blockIdx.x >> 7;
    int c = blockIdx.x & (NCH - 1);
    int i0 = c * TK;
    int wv = t >> 6, lane = t & 63;
    if (t < TK) idsl[t] = ids[b * LL + i0 + t];
    // wave wv stages rows [8wv, 8wv+8): one global_load_lds (1KB) per row
    {
        const float* src = Ktrev + (long)i0 * HH;
        #pragma unroll
        for (int r = 0; r < 8; ++r) {
            int row = wv * 8 + r;
            __builtin_amdgcn_global_load_lds(
                (const __attribute__((address_space(1))) void*)
                    (src + row * HH + lane * 4),
                (__attribute__((address_space(3))) void*)(&Kls[row * HH]),
                16, 0, 0);
        }
    }
    __syncthreads();   // drains vmcnt + lgkmcnt
    float acc = 0.0f;
    #pragma unroll 8
    for (int l = 0; l < TK; ++l) {
        int id = idsl[l];                        // uniform LDS broadcast
        float v = emb[(long)id * HH + t];        // coalesced 1KB/256thr
        acc = fmaf(v, Kls[l * HH + t], acc);     // conflict-free ds_read
    }
    atomicAdd(&y[b * HH + t], acc);              // device-scope f32 atomic
    asm volatile("s_waitcnt vmcnt(0)" ::: "memory");   // own adds committed
    __syncthreads();   // all 4 waves drained (compiler re-drains at barrier)
    if (t == 0) {
        int old = atomicAdd(&ticket[b], 1);      // relaxed returning RMW
        role = (old == NCH - 1);
    }
    __syncthreads();
    if (!role) return;

    // ---------------- finisher: this batch's output ----------------
    int idl = idsl[TK - 1];   // this block is chunk c; need token L-1:
    if (c != NCH - 1) idl = ids[b * LL + LL - 1];
    float yv = __hip_atomic_load(&y[b * HH + t], __ATOMIC_RELAXED,
                                 __HIP_MEMORY_SCOPE_AGENT);
    yv += emb[(long)idl * HH + t] * Dv[t];
    gs[t] = 0.5f * yv * (1.0f + erff(yv * 0.70710678118654752f));
    __syncthreads();
    // GEMV: wave wv owns o in [128wv, 128wv+128); one row-dot per iter
    float4 gr = ((const float4*)gs)[lane];
    #pragma unroll 4
    for (int oo = 0; oo < 128; ++oo) {
        int o = wv * 128 + oo;
        float4 wr = ((const float4*)(W + o * HH))[lane];
        float p = wr.x * gr.x + wr.y * gr.y + wr.z * gr.z + wr.w * gr.w;
        #pragma unroll
        for (int m = 32; m > 0; m >>= 1) p += __shfl_xor(p, m);
        if (lane == 0) zbuf[o] = p + bvec[o];
    }
    __syncthreads();
    float z1 = zbuf[t];
    float z2 = zbuf[t + HH];
    out[b * HH + t] = z1 * (1.0f / (1.0f + expf(-z2)));
}

extern "C" void kernel_launch(void* const* d_in, const int* in_sizes, int n_in,
                              void* d_out, int out_size, void* d_ws, size_t ws_size,
                              hipStream_t stream) {
    const int* input_ids = (const int*)d_in[0];
    const float* embedding = (const float*)d_in[1];
    const float* log_dt = (const float*)d_in[2];
    const float* A_log_re = (const float*)d_in[3];
    const float* A_im = (const float*)d_in[4];
    const float* B_re = (const float*)d_in[5];
    const float* B_im = (const float*)d_in[6];
    const float* C_re = (const float*)d_in[7];
    const float* C_im = (const float*)d_in[8];
    const float* D = (const float*)d_in[9];
    const float* W_out = (const float*)d_in[10];
    const float* b_out = (const float*)d_in[11];
    float* out = (float*)d_out;

    float* ws = (float*)d_ws;
    float* Ktrev = ws;                            // L*H floats
    float* y = ws + 1048576;                      // B*H floats
    int* ticket = (int*)(ws + 1050624);           // B ints

    kmat_kernel<<<HH, 512, 0, stream>>>(
        log_dt, A_log_re, A_im, B_re, B_im, C_re, C_im, Ktrev, y, ticket);

    gconv_kernel<<<BB * NCH, 256, 0, stream>>>(
        input_ids, embedding, Ktrev, y, ticket, D, W_out, b_out, out);
}

// Round 11
// 183.648 us; speedup vs baseline: 1.0819x; 1.0819x over previous
//
#include <hip/hip_runtime.h>
#include <math.h>

#define HH 256
#define NN 64
#define LL 4096
#define BB 8
#define TK 32            // tokens per gconv block
#define NCH (LL / TK)    // 128 chunks per batch

// ws layout (floats):
//   Ktrev (float [L][H])   @ 0        (1048576)   Ktrev[i][h] = K[h][L-1-i]
//   y     (float [B][H])   @ 1048576  (2048)      atomic-accumulated conv
//   ticket(int  [B])       @ 1050624  (8)

// k1: K-materialization, one block per h (proven spill-free scheme):
//   K[h,l] = Re( sum_n w[h,n] * dA[h,n]^l ),  w = 2*C0*dB
//   wave w owns l-range [512w,512w+512), lane owns l%64, n serial; pow
//   table dA_n^lane in padded LDS; store TRANSPOSED+reversed. Block 0 also
//   zero-inits y and the per-batch tickets (stream order: before k2).
__global__ __launch_bounds__(512) void kmat_kernel(
    const float* __restrict__ log_dt, const float* __restrict__ A_log_re,
    const float* __restrict__ A_im, const float* __restrict__ B_re,
    const float* __restrict__ B_im, const float* __restrict__ C_re,
    const float* __restrict__ C_im, float* __restrict__ Ktrev,
    float* __restrict__ y, int* __restrict__ ticket) {
    __shared__ struct {
        float powR[64][65]; float powI[64][65];
        float2 dAt[64]; float2 e64t[64]; float2 W2[8][64];
    } sk;
    int t = threadIdx.x;
    int h = blockIdx.x;
    int w = __builtin_amdgcn_readfirstlane(t >> 6);   // wave id 0..7
    int lane = t & 63;
    if (h == 0) {   // per-iteration init (ws is re-poisoned each iter)
        #pragma unroll
        for (int i = 0; i < BB * HH / 512; ++i) y[i * 512 + t] = 0.0f;
        if (t < BB) ticket[t] = 0;
    }
    // -- stage 1 (wave 0): per-n constants --
    if (t < NN) {
        int n = t;
        int idx = h * NN + n;
        float dt = expf(log_dt[h]);
        float Are = -expf(A_log_re[idx]);
        float Aim = A_im[idx];
        float ea = expf(dt * Are);
        float sn, cs;
        sincosf(dt * Aim, &sn, &cs);
        float dAre = ea * cs, dAim = ea * sn;
        float numre = dAre - 1.0f, numim = dAim;
        float den = Are * Are + Aim * Aim;
        float qre = (numre * Are + numim * Aim) / den;
        float qim = (numim * Are - numre * Aim) / den;
        float bre = B_re[idx], bim = B_im[idx];
        float dBre = bre * qre - bim * qim;
        float dBim = bre * qim + bim * qre;
        float cre = C_re[idx], cim = C_im[idx];
        float wre = 2.0f * (cre * dBre - cim * dBim);
        float wim = 2.0f * (cre * dBim + cim * dBre);
        sk.dAt[n] = make_float2(dAre, dAim);
        // e64 = dA^64 (6 squarings)
        float pr = dAre, pi = dAim;
        #pragma unroll
        for (int kq = 0; kq < 6; ++kq) {
            float nr = pr * pr - pi * pi;
            pi = 2.0f * pr * pi; pr = nr;
        }
        sk.e64t[n] = make_float2(pr, pi);
        // dA^512 = 3 more squarings
        #pragma unroll
        for (int kq = 0; kq < 3; ++kq) {
            float nr = pr * pr - pi * pi;
            pi = 2.0f * pr * pi; pr = nr;
        }
        // W2[k][n] = w_n * dA^(512k)
        float qr2 = wre, qi2 = wim;
        #pragma unroll
        for (int kk = 0; kk < 8; ++kk) {
            sk.W2[kk][n] = make_float2(qr2, qi2);
            float nr = qr2 * pr - qi2 * pi, ni = qr2 * pi + qi2 * pr;
            qr2 = nr; qi2 = ni;
        }
    }
    __syncthreads();
    // -- stage 2 (all waves): pow table, wave w fills rows 8w..8w+7 --
    {
        float2 a = sk.dAt[lane];             // dA_n, n = lane
        float br = a.x, bi = a.y;            // -> dA^8
        #pragma unroll
        for (int kq = 0; kq < 3; ++kq) {
            float nr = br * br - bi * bi;
            bi = 2.0f * br * bi; br = nr;
        }
        float pr = 1.0f, pi = 0.0f;          // d8^w (w uniform)
        #pragma unroll
        for (int bit = 0; bit < 3; ++bit) {
            if ((w >> bit) & 1) {
                float tr = pr * br - pi * bi;
                pi = pr * bi + pi * br; pr = tr;
            }
            float t2 = br * br - bi * bi;
            bi = 2.0f * br * bi; br = t2;
        }
        #pragma unroll
        for (int i = 0; i < 8; ++i) {        // pow[8w+i][n] = dA_n^(8w+i)
            sk.powR[8 * w + i][lane] = pr;
            sk.powI[8 * w + i][lane] = pi;
            float tr = pr * a.x - pi * a.y;
            pi = pr * a.y + pi * a.x; pr = tr;
        }
    }
    __syncthreads();
    // -- stage 3: thread owns l = 512w + 64j + lane, n serial --
    float kacc[8];
    #pragma unroll
    for (int j = 0; j < 8; ++j) kacc[j] = 0.0f;
    #pragma unroll 2
    for (int n = 0; n < NN; ++n) {
        float Pr = sk.powR[lane][n];         // conflict-free (pad 65)
        float Pi = sk.powI[lane][n];
        float2 E = sk.e64t[n];               // uniform broadcast
        float2 Wn = sk.W2[w][n];             // uniform broadcast
        float vr = Wn.x * Pr - Wn.y * Pi;
        float vi = Wn.x * Pi + Wn.y * Pr;
        #pragma unroll
        for (int j = 0; j < 8; ++j) {
            kacc[j] += vr;
            float tr = vr * E.x - vi * E.y;
            vi = vr * E.y + vi * E.x; vr = tr;
        }
    }
    // -- store transposed + reversed --
    #pragma unroll
    for (int j = 0; j < 8; ++j) {
        int l = w * 512 + j * 64 + lane;
        Ktrev[(long)(LL - 1 - l) * HH + h] = kacc[j];
    }
}

// k2: fused gather-conv + PARALLEL finisher. Block = (b, 32-token chunk).
// Phase 1: direct coalesced global reads of emb rows + Ktrev slice (no LDS
// staging -- each element used once), 32 FMA/thread, D-term folded into
// chunk NCH-1, one atomicAdd/thread into y[b][h]; vmcnt(0) drain; relaxed
// returning ticket (protocol correctness proven in R10).
// Phase 2: EVERY block finishes its own slice: after ticket[b]==NCH, block
// (b,c) computes z rows {2c, 2c+1, 2c+256, 2c+257} (one per wave) and the
// GLU pair out[b][2c..2c+1]. 1024-way parallel GEMV -- fixes R10's 8-block
// serialization. LDS ~1.3 KB -> capacity ~2048 blocks co-resident >> 1024,
// so the spin cannot deadlock.
__global__ __launch_bounds__(256) void gconv_out_kernel(
    const int* __restrict__ ids, const float* __restrict__ emb,
    const float* __restrict__ Ktrev, float* __restrict__ y,
    int* __restrict__ ticket, const float* __restrict__ Dv,
    const float* __restrict__ W, const float* __restrict__ bvec,
    float* __restrict__ out) {
    __shared__ int idsl[TK];
    __shared__ float gs[HH];
    __shared__ float zb[4];
    int t = threadIdx.x;
    int b = blockIdx.x >> 7;
    int c = blockIdx.x & (NCH - 1);
    int i0 = c * TK;
    int wv = t >> 6, lane = t & 63;
    if (t < TK) idsl[t] = ids[b * LL + i0 + t];
    __syncthreads();
    float acc = 0.0f, vlast = 0.0f;
    #pragma unroll
    for (int l = 0; l < TK; ++l) {
        int id = idsl[l];                            // uniform LDS broadcast
        float v = emb[(long)id * HH + t];            // coalesced 1KB/256thr
        float kv = Ktrev[(long)(i0 + l) * HH + t];   // coalesced, L2-hot
        acc = fmaf(v, kv, acc);
        if (l == TK - 1) vlast = v;
    }
    if (c == NCH - 1) acc = fmaf(vlast, Dv[t], acc);  // D-term: u[L-1]*D
    atomicAdd(&y[b * HH + t], acc);                   // device-scope f32
    asm volatile("s_waitcnt vmcnt(0)" ::: "memory");  // own adds committed
    __syncthreads();
    if (t == 0) {
        atomicAdd(&ticket[b], 1);                     // relaxed returning RMW
        while (__hip_atomic_load(ticket + b, __ATOMIC_RELAXED,
                                 __HIP_MEMORY_SCOPE_AGENT) < NCH)
            __builtin_amdgcn_s_sleep(2);
    }
    __syncthreads();

    // ---------------- finisher slice for (b, rows 2c/2c+1) ----------------
    float yv = __hip_atomic_load(&y[b * HH + t], __ATOMIC_RELAXED,
                                 __HIP_MEMORY_SCOPE_AGENT);
    gs[t] = 0.5f * yv * (1.0f + erff(yv * 0.70710678118654752f));
    __syncthreads();
    int o = 2 * c + (wv & 1) + (wv >> 1) * HH;        // wave -> z-row
    float4 wr = ((const float4*)(W + o * HH))[lane];
    float4 gr = ((const float4*)gs)[lane];
    float p = wr.x * gr.x + wr.y * gr.y + wr.z * gr.z + wr.w * gr.w;
    #pragma unroll
    for (int m = 32; m > 0; m >>= 1) p += __shfl_xor(p, m);
    if (lane == 0) zb[wv] = p + bvec[o];
    __syncthreads();
    if (t < 2) {
        float z1 = zb[t];          // z[2c+t]
        float z2 = zb[t + 2];      // z[2c+t+256]
        out[b * HH + 2 * c + t] = z1 * (1.0f / (1.0f + expf(-z2)));
    }
}

extern "C" void kernel_launch(void* const* d_in, const int* in_sizes, int n_in,
                              void* d_out, int out_size, void* d_ws, size_t ws_size,
                              hipStream_t stream) {
    const int* input_ids = (const int*)d_in[0];
    const float* embedding = (const float*)d_in[1];
    const float* log_dt = (const float*)d_in[2];
    const float* A_log_re = (const float*)d_in[3];
    const float* A_im = (const float*)d_in[4];
    const float* B_re = (const float*)d_in[5];
    const float* B_im = (const float*)d_in[6];
    const float* C_re = (const float*)d_in[7];
    const float* C_im = (const float*)d_in[8];
    const float* D = (const float*)d_in[9];
    const float* W_out = (const float*)d_in[10];
    const float* b_out = (const float*)d_in[11];
    float* out = (float*)d_out;

    float* ws = (float*)d_ws;
    float* Ktrev = ws;                            // L*H floats
    float* y = ws + 1048576;                      // B*H floats
    int* ticket = (int*)(ws + 1050624);           // B ints

    kmat_kernel<<<HH, 512, 0, stream>>>(
        log_dt, A_log_re, A_im, B_re, B_im, C_re, C_im, Ktrev, y, ticket);

    gconv_out_kernel<<<BB * NCH, 256, 0, stream>>>(
        input_ids, embedding, Ktrev, y, ticket, D, W_out, b_out, out);
}

// Round 12
// 180.772 us; speedup vs baseline: 1.0991x; 1.0159x over previous
//
#include <hip/hip_runtime.h>
#include <math.h>

#define HH 256
#define NN 64
#define LL 4096
#define BB 8
#define TK 32            // tokens per gconv block
#define NCH (LL / TK)    // 128 chunks per batch

// ws layout (floats):
//   Ktrev (float [L][H])   @ 0        (1048576)   Ktrev[i][h] = K[h][L-1-i]
//   y     (float [B][H])   @ 1048576  (2048)      atomic-accumulated conv
//   ticket(int  [B])       @ 1050624  (8)

// k1: K-materialization, one block per h (proven spill-free scheme):
//   K[h,l] = Re( sum_n w[h,n] * dA[h,n]^l ),  w = 2*C0*dB
//   wave w owns l-range [512w,512w+512), lane owns l%64, n serial; pow
//   table dA_n^lane in padded LDS; store TRANSPOSED+reversed. Block 0 also
//   zero-inits y and the per-batch tickets (stream order: before k2).
__global__ __launch_bounds__(512) void kmat_kernel(
    const float* __restrict__ log_dt, const float* __restrict__ A_log_re,
    const float* __restrict__ A_im, const float* __restrict__ B_re,
    const float* __restrict__ B_im, const float* __restrict__ C_re,
    const float* __restrict__ C_im, float* __restrict__ Ktrev,
    float* __restrict__ y, int* __restrict__ ticket) {
    __shared__ struct {
        float powR[64][65]; float powI[64][65];
        float2 dAt[64]; float2 e64t[64]; float2 W2[8][64];
    } sk;
    int t = threadIdx.x;
    int h = blockIdx.x;
    int w = __builtin_amdgcn_readfirstlane(t >> 6);   // wave id 0..7
    int lane = t & 63;
    if (h == 0) {   // per-iteration init (ws is re-poisoned each iter)
        #pragma unroll
        for (int i = 0; i < BB * HH / 512; ++i) y[i * 512 + t] = 0.0f;
        if (t < BB) ticket[t] = 0;
    }
    // -- stage 1 (wave 0): per-n constants --
    if (t < NN) {
        int n = t;
        int idx = h * NN + n;
        float dt = expf(log_dt[h]);
        float Are = -expf(A_log_re[idx]);
        float Aim = A_im[idx];
        float ea = expf(dt * Are);
        float sn, cs;
        sincosf(dt * Aim, &sn, &cs);
        float dAre = ea * cs, dAim = ea * sn;
        float numre = dAre - 1.0f, numim = dAim;
        float den = Are * Are + Aim * Aim;
        float qre = (numre * Are + numim * Aim) / den;
        float qim = (numim * Are - numre * Aim) / den;
        float bre = B_re[idx], bim = B_im[idx];
        float dBre = bre * qre - bim * qim;
        float dBim = bre * qim + bim * qre;
        float cre = C_re[idx], cim = C_im[idx];
        float wre = 2.0f * (cre * dBre - cim * dBim);
        float wim = 2.0f * (cre * dBim + cim * dBre);
        sk.dAt[n] = make_float2(dAre, dAim);
        // e64 = dA^64 (6 squarings)
        float pr = dAre, pi = dAim;
        #pragma unroll
        for (int kq = 0; kq < 6; ++kq) {
            float nr = pr * pr - pi * pi;
            pi = 2.0f * pr * pi; pr = nr;
        }
        sk.e64t[n] = make_float2(pr, pi);
        // dA^512 = 3 more squarings
        #pragma unroll
        for (int kq = 0; kq < 3; ++kq) {
            float nr = pr * pr - pi * pi;
            pi = 2.0f * pr * pi; pr = nr;
        }
        // W2[k][n] = w_n * dA^(512k)
        float qr2 = wre, qi2 = wim;
        #pragma unroll
        for (int kk = 0; kk < 8; ++kk) {
            sk.W2[kk][n] = make_float2(qr2, qi2);
            float nr = qr2 * pr - qi2 * pi, ni = qr2 * pi + qi2 * pr;
            qr2 = nr; qi2 = ni;
        }
    }
    __syncthreads();
    // -- stage 2 (all waves): pow table, wave w fills rows 8w..8w+7 --
    {
        float2 a = sk.dAt[lane];             // dA_n, n = lane
        float br = a.x, bi = a.y;            // -> dA^8
        #pragma unroll
        for (int kq = 0; kq < 3; ++kq) {
            float nr = br * br - bi * bi;
            bi = 2.0f * br * bi; br = nr;
        }
        float pr = 1.0f, pi = 0.0f;          // d8^w (w uniform)
        #pragma unroll
        for (int bit = 0; bit < 3; ++bit) {
            if ((w >> bit) & 1) {
                float tr = pr * br - pi * bi;
                pi = pr * bi + pi * br; pr = tr;
            }
            float t2 = br * br - bi * bi;
            bi = 2.0f * br * bi; br = t2;
        }
        #pragma unroll
        for (int i = 0; i < 8; ++i) {        // pow[8w+i][n] = dA_n^(8w+i)
            sk.powR[8 * w + i][lane] = pr;
            sk.powI[8 * w + i][lane] = pi;
            float tr = pr * a.x - pi * a.y;
            pi = pr * a.y + pi * a.x; pr = tr;
        }
    }
    __syncthreads();
    // -- stage 3: thread owns l = 512w + 64j + lane, n serial --
    float kacc[8];
    #pragma unroll
    for (int j = 0; j < 8; ++j) kacc[j] = 0.0f;
    #pragma unroll 2
    for (int n = 0; n < NN; ++n) {
        float Pr = sk.powR[lane][n];         // conflict-free (pad 65)
        float Pi = sk.powI[lane][n];
        float2 E = sk.e64t[n];               // uniform broadcast
        float2 Wn = sk.W2[w][n];             // uniform broadcast
        float vr = Wn.x * Pr - Wn.y * Pi;
        float vi = Wn.x * Pi + Wn.y * Pr;
        #pragma unroll
        for (int j = 0; j < 8; ++j) {
            kacc[j] += vr;
            float tr = vr * E.x - vi * E.y;
            vi = vr * E.y + vi * E.x; vr = tr;
        }
    }
    // -- store transposed + reversed --
    #pragma unroll
    for (int j = 0; j < 8; ++j) {
        int l = w * 512 + j * 64 + lane;
        Ktrev[(long)(LL - 1 - l) * HH + h] = kacc[j];
    }
}

// k2: fused gather-conv + PARALLEL finisher (R11 structure, MLP fix).
// Phase 1: preload ALL 32 (emb, Ktrev) pairs into registers with static
// indexing -> 64 loads in flight per thread before the first wait (R11's
// serial fmaf chain held ~4: 32 x 900cy latency-bound at 255 GB/s). Then
// reduce, fold D-term into chunk NCH-1, one atomicAdd/thread into y[b][h];
// vmcnt(0) drain; relaxed returning ticket (protocol proven R10/R11).
// Phase 2: every block finishes its own slice (z rows 2c,2c+1,+256 each;
// GLU pair out[b][2c..2c+1]); spin tolerates partial residency (batch
// groups contiguous, capacity >> 128-block batch granule).
__global__ __launch_bounds__(256) void gconv_out_kernel(
    const int* __restrict__ ids, const float* __restrict__ emb,
    const float* __restrict__ Ktrev, float* __restrict__ y,
    int* __restrict__ ticket, const float* __restrict__ Dv,
    const float* __restrict__ W, const float* __restrict__ bvec,
    float* __restrict__ out) {
    __shared__ int idsl[TK];
    __shared__ float gs[HH];
    __shared__ float zb[4];
    int t = threadIdx.x;
    int b = blockIdx.x >> 7;
    int c = blockIdx.x & (NCH - 1);
    int i0 = c * TK;
    int wv = t >> 6, lane = t & 63;
    if (t < TK) idsl[t] = ids[b * LL + i0 + t];
    __syncthreads();
    // ---- MLP fix: all 64 loads issued before first use ----
    float ve[TK], kv[TK];
    #pragma unroll
    for (int l = 0; l < TK; ++l) {
        ve[l] = emb[(long)idsl[l] * HH + t];         // coalesced 1KB/256thr
        kv[l] = Ktrev[(long)(i0 + l) * HH + t];      // coalesced, L3-hot
    }
    float acc = 0.0f;
    #pragma unroll
    for (int l = 0; l < TK; ++l) acc = fmaf(ve[l], kv[l], acc);
    if (c == NCH - 1) acc = fmaf(ve[TK - 1], Dv[t], acc);  // D-term u[L-1]*D
    atomicAdd(&y[b * HH + t], acc);                   // device-scope f32
    asm volatile("s_waitcnt vmcnt(0)" ::: "memory");  // own adds committed
    __syncthreads();
    if (t == 0) {
        atomicAdd(&ticket[b], 1);                     // relaxed returning RMW
        while (__hip_atomic_load(ticket + b, __ATOMIC_RELAXED,
                                 __HIP_MEMORY_SCOPE_AGENT) < NCH)
            __builtin_amdgcn_s_sleep(2);
    }
    __syncthreads();

    // ---------------- finisher slice for (b, rows 2c/2c+1) ----------------
    float yv = __hip_atomic_load(&y[b * HH + t], __ATOMIC_RELAXED,
                                 __HIP_MEMORY_SCOPE_AGENT);
    gs[t] = 0.5f * yv * (1.0f + erff(yv * 0.70710678118654752f));
    __syncthreads();
    int o = 2 * c + (wv & 1) + (wv >> 1) * HH;        // wave -> z-row
    float4 wr = ((const float4*)(W + o * HH))[lane];
    float4 gr = ((const float4*)gs)[lane];
    float p = wr.x * gr.x + wr.y * gr.y + wr.z * gr.z + wr.w * gr.w;
    #pragma unroll
    for (int m = 32; m > 0; m >>= 1) p += __shfl_xor(p, m);
    if (lane == 0) zb[wv] = p + bvec[o];
    __syncthreads();
    if (t < 2) {
        float z1 = zb[t];          // z[2c+t]
        float z2 = zb[t + 2];      // z[2c+t+256]
        out[b * HH + 2 * c + t] = z1 * (1.0f / (1.0f + expf(-z2)));
    }
}

extern "C" void kernel_launch(void* const* d_in, const int* in_sizes, int n_in,
                              void* d_out, int out_size, void* d_ws, size_t ws_size,
                              hipStream_t stream) {
    const int* input_ids = (const int*)d_in[0];
    const float* embedding = (const float*)d_in[1];
    const float* log_dt = (const float*)d_in[2];
    const float* A_log_re = (const float*)d_in[3];
    const float* A_im = (const float*)d_in[4];
    const float* B_re = (const float*)d_in[5];
    const float* B_im = (const float*)d_in[6];
    const float* C_re = (const float*)d_in[7];
    const float* C_im = (const float*)d_in[8];
    const float* D = (const float*)d_in[9];
    const float* W_out = (const float*)d_in[10];
    const float* b_out = (const float*)d_in[11];
    float* out = (float*)d_out;

    float* ws = (float*)d_ws;
    float* Ktrev = ws;                            // L*H floats
    float* y = ws + 1048576;                      // B*H floats
    int* ticket = (int*)(ws + 1050624);           // B ints

    kmat_kernel<<<HH, 512, 0, stream>>>(
        log_dt, A_log_re, A_im, B_re, B_im, C_re, C_im, Ktrev, y, ticket);

    gconv_out_kernel<<<BB * NCH, 256, 0, stream>>>(
        input_ids, embedding, Ktrev, y, ticket, D, W_out, b_out, out);
}

// Round 13
// 128.934 us; speedup vs baseline: 1.5410x; 1.4021x over previous
//
#include <hip/hip_runtime.h>
#include <math.h>

#define HH 256
#define NN 64
#define LL 4096
#define BB 8
#define TK 16            // tokens per gconv block
#define NCH (LL / TK)    // 256 chunks per batch

// ws layout (floats):
//   Ktrev (float [L][H])   @ 0        (1048576)   Ktrev[i][h] = K[h][L-1-i]
//   y     (float [B][H])   @ 1048576  (2048)      atomic-accumulated conv

// k1: K-materialization, one block per h (proven spill-free scheme):
//   K[h,l] = Re( sum_n w[h,n] * dA[h,n]^l ),  w = 2*C0*dB
//   wave w owns l-range [512w,512w+512), lane owns l%64, n serial; pow
//   table dA_n^lane in padded LDS; store TRANSPOSED+reversed. Block 0 also
//   zero-inits y (stream order: lands before gconv's atomics).
__global__ __launch_bounds__(512) void kmat_kernel(
    const float* __restrict__ log_dt, const float* __restrict__ A_log_re,
    const float* __restrict__ A_im, const float* __restrict__ B_re,
    const float* __restrict__ B_im, const float* __restrict__ C_re,
    const float* __restrict__ C_im, float* __restrict__ Ktrev,
    float* __restrict__ y) {
    __shared__ struct {
        float powR[64][65]; float powI[64][65];
        float2 dAt[64]; float2 e64t[64]; float2 W2[8][64];
    } sk;
    int t = threadIdx.x;
    int h = blockIdx.x;
    int w = __builtin_amdgcn_readfirstlane(t >> 6);   // wave id 0..7
    int lane = t & 63;
    if (h == 0) {   // per-iteration init (ws is re-poisoned each iter)
        #pragma unroll
        for (int i = 0; i < BB * HH / 512; ++i) y[i * 512 + t] = 0.0f;
    }
    // -- stage 1 (wave 0): per-n constants --
    if (t < NN) {
        int n = t;
        int idx = h * NN + n;
        float dt = expf(log_dt[h]);
        float Are = -expf(A_log_re[idx]);
        float Aim = A_im[idx];
        float ea = expf(dt * Are);
        float sn, cs;
        sincosf(dt * Aim, &sn, &cs);
        float dAre = ea * cs, dAim = ea * sn;
        float numre = dAre - 1.0f, numim = dAim;
        float den = Are * Are + Aim * Aim;
        float qre = (numre * Are + numim * Aim) / den;
        float qim = (numim * Are - numre * Aim) / den;
        float bre = B_re[idx], bim = B_im[idx];
        float dBre = bre * qre - bim * qim;
        float dBim = bre * qim + bim * qre;
        float cre = C_re[idx], cim = C_im[idx];
        float wre = 2.0f * (cre * dBre - cim * dBim);
        float wim = 2.0f * (cre * dBim + cim * dBre);
        sk.dAt[n] = make_float2(dAre, dAim);
        // e64 = dA^64 (6 squarings)
        float pr = dAre, pi = dAim;
        #pragma unroll
        for (int kq = 0; kq < 6; ++kq) {
            float nr = pr * pr - pi * pi;
            pi = 2.0f * pr * pi; pr = nr;
        }
        sk.e64t[n] = make_float2(pr, pi);
        // dA^512 = 3 more squarings
        #pragma unroll
        for (int kq = 0; kq < 3; ++kq) {
            float nr = pr * pr - pi * pi;
            pi = 2.0f * pr * pi; pr = nr;
        }
        // W2[k][n] = w_n * dA^(512k)
        float qr2 = wre, qi2 = wim;
        #pragma unroll
        for (int kk = 0; kk < 8; ++kk) {
            sk.W2[kk][n] = make_float2(qr2, qi2);
            float nr = qr2 * pr - qi2 * pi, ni = qr2 * pi + qi2 * pr;
            qr2 = nr; qi2 = ni;
        }
    }
    __syncthreads();
    // -- stage 2 (all waves): pow table, wave w fills rows 8w..8w+7 --
    {
        float2 a = sk.dAt[lane];             // dA_n, n = lane
        float br = a.x, bi = a.y;            // -> dA^8
        #pragma unroll
        for (int kq = 0; kq < 3; ++kq) {
            float nr = br * br - bi * bi;
            bi = 2.0f * br * bi; br = nr;
        }
        float pr = 1.0f, pi = 0.0f;          // d8^w (w uniform)
        #pragma unroll
        for (int bit = 0; bit < 3; ++bit) {
            if ((w >> bit) & 1) {
                float tr = pr * br - pi * bi;
                pi = pr * bi + pi * br; pr = tr;
            }
            float t2 = br * br - bi * bi;
            bi = 2.0f * br * bi; br = t2;
        }
        #pragma unroll
        for (int i = 0; i < 8; ++i) {        // pow[8w+i][n] = dA_n^(8w+i)
            sk.powR[8 * w + i][lane] = pr;
            sk.powI[8 * w + i][lane] = pi;
            float tr = pr * a.x - pi * a.y;
            pi = pr * a.y + pi * a.x; pr = tr;
        }
    }
    __syncthreads();
    // -- stage 3: thread owns l = 512w + 64j + lane, n serial --
    float kacc[8];
    #pragma unroll
    for (int j = 0; j < 8; ++j) kacc[j] = 0.0f;
    #pragma unroll 2
    for (int n = 0; n < NN; ++n) {
        float Pr = sk.powR[lane][n];         // conflict-free (pad 65)
        float Pi = sk.powI[lane][n];
        float2 E = sk.e64t[n];               // uniform broadcast
        float2 Wn = sk.W2[w][n];             // uniform broadcast
        float vr = Wn.x * Pr - Wn.y * Pi;
        float vi = Wn.x * Pi + Wn.y * Pr;
        #pragma unroll
        for (int j = 0; j < 8; ++j) {
            kacc[j] += vr;
            float tr = vr * E.x - vi * E.y;
            vi = vr * E.y + vi * E.x; vr = tr;
        }
    }
    // -- store transposed + reversed --
    #pragma unroll
    for (int j = 0; j < 8; ++j) {
        int l = w * 512 + j * 64 + lane;
        Ktrev[(long)(LL - 1 - l) * HH + h] = kacc[j];
    }
}

// k2: gather-conv, max-occupancy latency-hiding version. Block = (b,
// 16-token chunk): 2048 blocks, ZERO LDS, VGPR ~48 -> 8 blocks/CU = 32
// waves/CU. ids read as wave-uniform scalars (s_load); all 32 loads issued
// before any FMA, pinned by sched_barrier(0) (R12's preload was re-sunk by
// the compiler -- VGPR stayed 44; this fences it). D-term folded into the
// last chunk. One atomicAdd/thread into y (R9-proven, no spin/ticket).
__global__ __launch_bounds__(256) void gconv_kernel(
    const int* __restrict__ ids, const float* __restrict__ emb,
    const float* __restrict__ Ktrev, float* __restrict__ y,
    const float* __restrict__ Dv) {
    int t = threadIdx.x;
    int b = blockIdx.x >> 8;
    int c = blockIdx.x & (NCH - 1);
    int i0 = c * TK;
    const int* idp = ids + b * LL + i0;      // uniform -> s_load_dwordx8
    float ve[TK], kv[TK];
    #pragma unroll
    for (int l = 0; l < TK; ++l) {
        ve[l] = emb[(long)idp[l] * HH + t];        // saddr + t*4, coalesced
        kv[l] = Ktrev[(long)(i0 + l) * HH + t];    // coalesced, L3-hot
    }
    __builtin_amdgcn_sched_barrier(0);       // loads may not sink past here
    float acc = 0.0f;
    #pragma unroll
    for (int l = 0; l < TK; ++l) acc = fmaf(ve[l], kv[l], acc);
    if (c == NCH - 1) acc = fmaf(ve[TK - 1], Dv[t], acc);  // u[L-1]*D
    atomicAdd(&y[b * HH + t], acc);          // device-scope f32 atomic
}

// k3: GELU + output projection + GLU (R9's proven 1024-block shape).
// Block owns (b, 2 h's); y already contains the D-term.
__global__ __launch_bounds__(256) void out_kernel(
    const float* __restrict__ y, const float* __restrict__ W,
    const float* __restrict__ bvec, float* __restrict__ out) {
    int b = blockIdx.x >> 7;
    int tile = blockIdx.x & 127;
    int t = threadIdx.x;
    int w = t >> 6, lane = t & 63;
    __shared__ float gs[HH];
    __shared__ float zb[4];
    float yv = y[b * HH + t];
    gs[t] = 0.5f * yv * (1.0f + erff(yv * 0.70710678118654752f));
    __syncthreads();
    int hh = tile * 2 + (w >> 1);
    int o = (w & 1) * HH + hh;
    float4 wv4 = ((const float4*)(W + o * HH))[lane];
    float4 gv4 = ((const float4*)gs)[lane];
    float p = wv4.x * gv4.x + wv4.y * gv4.y + wv4.z * gv4.z + wv4.w * gv4.w;
    #pragma unroll
    for (int m = 32; m > 0; m >>= 1) p += __shfl_xor(p, m);
    if (lane == 0) zb[w] = p + bvec[o];
    __syncthreads();
    if (t < 2) {
        int hq = tile * 2 + t;
        float z1 = zb[t * 2 + 0];
        float z2 = zb[t * 2 + 1];
        out[b * HH + hq] = z1 * (1.0f / (1.0f + expf(-z2)));
    }
}

extern "C" void kernel_launch(void* const* d_in, const int* in_sizes, int n_in,
                              void* d_out, int out_size, void* d_ws, size_t ws_size,
                              hipStream_t stream) {
    const int* input_ids = (const int*)d_in[0];
    const float* embedding = (const float*)d_in[1];
    const float* log_dt = (const float*)d_in[2];
    const float* A_log_re = (const float*)d_in[3];
    const float* A_im = (const float*)d_in[4];
    const float* B_re = (const float*)d_in[5];
    const float* B_im = (const float*)d_in[6];
    const float* C_re = (const float*)d_in[7];
    const float* C_im = (const float*)d_in[8];
    const float* D = (const float*)d_in[9];
    const float* W_out = (const float*)d_in[10];
    const float* b_out = (const float*)d_in[11];
    float* out = (float*)d_out;

    float* ws = (float*)d_ws;
    float* Ktrev = ws;                            // L*H floats
    float* y = ws + 1048576;                      // B*H floats

    kmat_kernel<<<HH, 512, 0, stream>>>(
        log_dt, A_log_re, A_im, B_re, B_im, C_re, C_im, Ktrev, y);

    gconv_kernel<<<BB * NCH, 256, 0, stream>>>(
        input_ids, embedding, Ktrev, y, D);

    out_kernel<<<BB * 128, 256, 0, stream>>>(
        y, W_out, b_out, out);
}

// Round 14
// 119.318 us; speedup vs baseline: 1.6652x; 1.0806x over previous
//
#include <hip/hip_runtime.h>
#include <math.h>

#define HH 256
#define NN 64
#define LL 4096
#define BB 8

// ws layout (floats):
//   u_ws (float [B][H][L])     @ 327680    (8388608)
//   g    (float [B][H])        @ 10813440  (2048)
//   Krev (float [H][L])        @ 10815488  (1048576)   K[h, L-1-l]

// k1: blocks [0,512) = embedding gather+transpose (proven);
//     blocks [512,768) = K-materialization, one block per h:
//       K[h,l] = Re( sum_n w[h,n] * dA[h,n]^l ),  w = 2*C0*dB
//     wave w owns l-range [512w,512w+512), lane owns l%64, n serial; pow
//     table dA_n^lane in padded LDS (bank = (lane+n)%32, conflict-free);
//     per-n constants are uniform broadcasts. No atomics, no spill.
__global__ __launch_bounds__(512) void frontend_kernel(
    const int* __restrict__ ids, const float* __restrict__ emb,
    const float* __restrict__ log_dt, const float* __restrict__ A_log_re,
    const float* __restrict__ A_im, const float* __restrict__ B_re,
    const float* __restrict__ B_im, const float* __restrict__ C_re,
    const float* __restrict__ C_im,
    float* __restrict__ u_ws, float* __restrict__ Krev) {
    __shared__ union {
        struct { int ids_s[64]; float tb[2][64][65]; } a;     // 33.5 KB
        struct { float powR[64][65]; float powI[64][65];      // 33.3 KB
                 float2 dAt[64]; float2 e64t[64]; float2 W2[8][64]; } k;
    } sm;
    int t = threadIdx.x;
    if (blockIdx.x < BB * 64) {
        // ---------------- gather + transpose ----------------
        int b = blockIdx.x >> 6;
        int tile = blockIdx.x & 63;
        int w = t >> 6;           // wave id 0..7
        int lane = t & 63;
        int rq = lane >> 4;       // row-within-quad 0..3
        int k = lane & 15;        // float4 column 0..15
        if (t < 64) sm.a.ids_s[t] = ids[b * LL + tile * 64 + t];
        __syncthreads();
        {
            int r0 = w * 8 + rq;
            float4 v0 = *(const float4*)(emb + (long)sm.a.ids_s[r0] * HH + 4 * k);
            float4 v1 = *(const float4*)(emb + (long)sm.a.ids_s[r0 + 4] * HH + 4 * k);
            sm.a.tb[0][r0][4 * k + 0] = v0.x;
            sm.a.tb[0][r0][4 * k + 1] = v0.y;
            sm.a.tb[0][r0][4 * k + 2] = v0.z;
            sm.a.tb[0][r0][4 * k + 3] = v0.w;
            sm.a.tb[0][r0 + 4][4 * k + 0] = v1.x;
            sm.a.tb[0][r0 + 4][4 * k + 1] = v1.y;
            sm.a.tb[0][r0 + 4][4 * k + 2] = v1.z;
            sm.a.tb[0][r0 + 4][4 * k + 3] = v1.w;
        }
        __syncthreads();
        #pragma unroll
        for (int c4 = 0; c4 < 4; ++c4) {
            int cur = c4 & 1;
            float4 v0, v1;
            if (c4 < 3) {
                int r0 = w * 8 + rq;
                v0 = *(const float4*)(emb + (long)sm.a.ids_s[r0] * HH +
                                      (c4 + 1) * 64 + 4 * k);
                v1 = *(const float4*)(emb + (long)sm.a.ids_s[r0 + 4] * HH +
                                      (c4 + 1) * 64 + 4 * k);
            }
            #pragma unroll
            for (int it = 0; it < 2; ++it) {
                int hq = w * 8 + it * 4 + rq;
                int s0 = 4 * k;
                float4 o;
                o.x = sm.a.tb[cur][s0 + 0][hq];
                o.y = sm.a.tb[cur][s0 + 1][hq];
                o.z = sm.a.tb[cur][s0 + 2][hq];
                o.w = sm.a.tb[cur][s0 + 3][hq];
                *(float4*)(u_ws + ((long)(b * HH + c4 * 64 + hq)) * LL +
                           tile * 64 + s0) = o;
            }
            if (c4 < 3) {
                int r0 = w * 8 + rq;
                sm.a.tb[cur ^ 1][r0][4 * k + 0] = v0.x;
                sm.a.tb[cur ^ 1][r0][4 * k + 1] = v0.y;
                sm.a.tb[cur ^ 1][r0][4 * k + 2] = v0.z;
                sm.a.tb[cur ^ 1][r0][4 * k + 3] = v0.w;
                sm.a.tb[cur ^ 1][r0 + 4][4 * k + 0] = v1.x;
                sm.a.tb[cur ^ 1][r0 + 4][4 * k + 1] = v1.y;
                sm.a.tb[cur ^ 1][r0 + 4][4 * k + 2] = v1.z;
                sm.a.tb[cur ^ 1][r0 + 4][4 * k + 3] = v1.w;
            }
            __syncthreads();
        }
    } else {
        // ---------------- K-materialization (one block per h) ----------------
        int h = blockIdx.x - BB * 64;
        int w = __builtin_amdgcn_readfirstlane(t >> 6);   // wave id 0..7
        int lane = t & 63;
        // -- stage 1 (wave 0): per-n constants --
        if (t < NN) {
            int n = t;
            int idx = h * NN + n;
            float dt = expf(log_dt[h]);
            float Are = -expf(A_log_re[idx]);
            float Aim = A_im[idx];
            float ea = expf(dt * Are);
            float sn, cs;
            sincosf(dt * Aim, &sn, &cs);
            float dAre = ea * cs, dAim = ea * sn;
            float numre = dAre - 1.0f, numim = dAim;
            float den = Are * Are + Aim * Aim;
            float qre = (numre * Are + numim * Aim) / den;
            float qim = (numim * Are - numre * Aim) / den;
            float bre = B_re[idx], bim = B_im[idx];
            float dBre = bre * qre - bim * qim;
            float dBim = bre * qim + bim * qre;
            float cre = C_re[idx], cim = C_im[idx];
            float wre = 2.0f * (cre * dBre - cim * dBim);
            float wim = 2.0f * (cre * dBim + cim * dBre);
            sm.k.dAt[n] = make_float2(dAre, dAim);
            // e64 = dA^64 (6 squarings)
            float pr = dAre, pi = dAim;
            #pragma unroll
            for (int kq = 0; kq < 6; ++kq) {
                float nr = pr * pr - pi * pi;
                pi = 2.0f * pr * pi; pr = nr;
            }
            sm.k.e64t[n] = make_float2(pr, pi);
            // dA^512 = 3 more squarings
            #pragma unroll
            for (int kq = 0; kq < 3; ++kq) {
                float nr = pr * pr - pi * pi;
                pi = 2.0f * pr * pi; pr = nr;
            }
            // W2[k][n] = w_n * dA^(512k)
            float qr2 = wre, qi2 = wim;
            #pragma unroll
            for (int kk = 0; kk < 8; ++kk) {
                sm.k.W2[kk][n] = make_float2(qr2, qi2);
                float nr = qr2 * pr - qi2 * pi, ni = qr2 * pi + qi2 * pr;
                qr2 = nr; qi2 = ni;
            }
        }
        __syncthreads();
        // -- stage 2 (all waves): pow table, wave w covers rows 8w..8w+7 --
        {
            float2 a = sm.k.dAt[lane];             // dA_n, n = lane
            float br = a.x, bi = a.y;              // -> dA^8
            #pragma unroll
            for (int kq = 0; kq < 3; ++kq) {
                float nr = br * br - bi * bi;
                bi = 2.0f * br * bi; br = nr;
            }
            float pr = 1.0f, pi = 0.0f;            // d8^w (w uniform)
            #pragma unroll
            for (int bit = 0; bit < 3; ++bit) {
                if ((w >> bit) & 1) {
                    float tr = pr * br - pi * bi;
                    pi = pr * bi + pi * br; pr = tr;
                }
                float t2 = br * br - bi * bi;
                bi = 2.0f * br * bi; br = t2;
            }
            #pragma unroll
            for (int i = 0; i < 8; ++i) {          // pow[8w+i][n] = dA_n^(8w+i)
                sm.k.powR[8 * w + i][lane] = pr;
                sm.k.powI[8 * w + i][lane] = pi;
                float tr = pr * a.x - pi * a.y;
                pi = pr * a.y + pi * a.x; pr = tr;
            }
        }
        __syncthreads();
        // -- stage 3: thread owns l = 512w + 64j + lane, n serial --
        float kacc[8];
        #pragma unroll
        for (int j = 0; j < 8; ++j) kacc[j] = 0.0f;
        #pragma unroll 2
        for (int n = 0; n < NN; ++n) {
            float Pr = sm.k.powR[lane][n];         // conflict-free (pad 65)
            float Pi = sm.k.powI[lane][n];
            float2 E = sm.k.e64t[n];               // uniform broadcast
            float2 Wn = sm.k.W2[w][n];             // uniform broadcast
            float vr = Wn.x * Pr - Wn.y * Pi;
            float vi = Wn.x * Pi + Wn.y * Pr;
            #pragma unroll
            for (int j = 0; j < 8; ++j) {
                kacc[j] += vr;
                float tr = vr * E.x - vi * E.y;
                vi = vr * E.y + vi * E.x; vr = tr;
            }
        }
        // -- store reversed: Krev[h][L-1-l] = K[h][l] --
        #pragma unroll
        for (int j = 0; j < 8; ++j) {
            int l = w * 512 + j * 64 + lane;
            Krev[h * LL + (LL - 1 - l)] = kacc[j];
        }
    }
}

// k2: conv -- y[b,h] = sum_t u[t]*Krev[t] + D[h]*u[L-1], GELU -> g.
// Pure streaming dot: 2048 blocks x 256 threads, 16 floats per thread.
__global__ __launch_bounds__(256) void conv_kernel(
    const float* __restrict__ u_ws, const float* __restrict__ Krev,
    const float* __restrict__ Dv, float* __restrict__ g) {
    __shared__ float partial[4];
    int t = threadIdx.x;
    int bh = blockIdx.x;
    int h = bh & (HH - 1);
    const float4* up = (const float4*)(u_ws + (long)bh * LL);
    const float4* kp = (const float4*)(Krev + h * LL);
    float acc = 0.0f;
    #pragma unroll
    for (int i = 0; i < 4; ++i) {      // instr i: lanes contiguous 4KB
        float4 uv = up[i * 256 + t];
        float4 kv = kp[i * 256 + t];
        acc += uv.x * kv.x + uv.y * kv.y + uv.z * kv.z + uv.w * kv.w;
    }
    #pragma unroll
    for (int m = 32; m > 0; m >>= 1) acc += __shfl_xor(acc, m);
    if ((t & 63) == 0) partial[t >> 6] = acc;
    __syncthreads();
    if (t == 0) {
        float y = partial[0] + partial[1] + partial[2] + partial[3]
                + u_ws[(long)bh * LL + LL - 1] * Dv[h];
        float ge = 0.5f * y * (1.0f + erff(y * 0.70710678118654752f));
        g[bh] = ge;
    }
}

// k3: output projection + GLU. grid = B*128 (2 h per block), block = 256.
__global__ __launch_bounds__(256) void out_kernel(
    const float* __restrict__ g, const float* __restrict__ W,
    const float* __restrict__ bvec, float* __restrict__ out) {
    int b = blockIdx.x >> 7;
    int tile = blockIdx.x & 127;
    int t = threadIdx.x;
    int w = t >> 6, lane = t & 63;
    __shared__ float gs[HH];
    __shared__ float zb[4];
    gs[t] = g[b * HH + t];
    __syncthreads();
    int hh = tile * 2 + (w >> 1);
    int o = (w & 1) * HH + hh;
    float4 wv4 = ((const float4*)(W + o * HH))[lane];
    float4 gv4 = ((const float4*)gs)[lane];
    float p = wv4.x * gv4.x + wv4.y * gv4.y + wv4.z * gv4.z + wv4.w * gv4.w;
    #pragma unroll
    for (int m = 32; m > 0; m >>= 1) p += __shfl_xor(p, m);
    if (lane == 0) zb[w] = p + bvec[o];
    __syncthreads();
    if (t < 2) {
        int hq = tile * 2 + t;
        float z1 = zb[t * 2 + 0];
        float z2 = zb[t * 2 + 1];
        out[b * HH + hq] = z1 * (1.0f / (1.0f + expf(-z2)));
    }
}

extern "C" void kernel_launch(void* const* d_in, const int* in_sizes, int n_in,
                              void* d_out, int out_size, void* d_ws, size_t ws_size,
                              hipStream_t stream) {
    const int* input_ids = (const int*)d_in[0];
    const float* embedding = (const float*)d_in[1];
    const float* log_dt = (const float*)d_in[2];
    const float* A_log_re = (const float*)d_in[3];
    const float* A_im = (const float*)d_in[4];
    const float* B_re = (const float*)d_in[5];
    const float* B_im = (const float*)d_in[6];
    const float* C_re = (const float*)d_in[7];
    const float* C_im = (const float*)d_in[8];
    const float* D = (const float*)d_in[9];
    const float* W_out = (const float*)d_in[10];
    const float* b_out = (const float*)d_in[11];
    float* out = (float*)d_out;

    float* ws = (float*)d_ws;
    float* u_ws = ws + 327680;                    // B*H*L floats
    float* g = ws + 10813440;                     // B*H floats
    float* Krev = ws + 10815488;                  // H*L floats

    frontend_kernel<<<BB * 64 + HH, 512, 0, stream>>>(
        input_ids, embedding, log_dt, A_log_re, A_im, B_re, B_im, C_re, C_im,
        u_ws, Krev);

    conv_kernel<<<BB * HH, 256, 0, stream>>>(u_ws, Krev, D, g);

    out_kernel<<<BB * 128, 256, 0, stream>>>(g, W_out, b_out, out);
}